// Round 6
// baseline (1149.944 us; speedup 1.0000x reference)
//
#include <hip/hip_runtime.h>
#include <math.h>

#define BN_RS 0.9995003746877732f

typedef unsigned short u16;
typedef _Float16 f16;
typedef __attribute__((ext_vector_type(8))) _Float16 h8v;     // 8 f16 (A/B frag)
typedef __attribute__((ext_vector_type(4))) _Float16 h4v;     // packed 4 f16 (8B)
typedef __attribute__((ext_vector_type(4))) float f32x4;      // C/D frag

#define AS1c(p) ((const __attribute__((address_space(1))) void*)(p))
#define AS3(p)  ((__attribute__((address_space(3))) void*)(p))

// ---------------- helpers ----------------
__device__ __forceinline__ unsigned f2mono(float f){
  unsigned u = __float_as_uint(f);
  return (u & 0x80000000u) ? ~u : (u | 0x80000000u);
}
__device__ __forceinline__ float mono2f(unsigned m){
  unsigned u = (m & 0x80000000u) ? (m & 0x7FFFFFFFu) : ~m;
  return __uint_as_float(u);
}
__device__ __forceinline__ float silu_fast(float x){ return x / (1.f + __expf(-x)); }
__device__ __forceinline__ float silu_f64(float x){
  double e = exp(-(double)x);
  return (float)((double)x / (1.0 + e));
}

// ---------------- ws layout (bytes) ----------------
constexpr size_t OFF_T9   = 0;         //  4*9*4
constexpr size_t OFF_XM   = 1024;      //  4*128*4 (mono uints)
constexpr size_t OFF_PC4  = 4096;      //  8192*16
constexpr size_t OFF_OUT  = 139264;    //  21760*4
constexpr size_t OFF_C1T  = 227328;    //  512*32*2
constexpr size_t OFF_REST = 262144;    //  512*512*2
constexpr size_t OFF_B0T  = 786432;    //  512*512*2
constexpr size_t OFF_B1T  = 1310720;   //  256*512*2
constexpr size_t OFF_B2T  = 1572864;   //  176*256*2
constexpr size_t OFF_F9   = 1703936;   //  8192*32*16*2

// ---------------- T-Net stage 1 ----------------
__global__ void tnet1_kernel(const float* __restrict__ pts, const float* __restrict__ t_cw,
                             const float* __restrict__ t_cb, const float* __restrict__ t_g1,
                             const float* __restrict__ t_b1, unsigned* __restrict__ xm_mono){
  int u = threadIdx.x;                 // 0..127
  int b = blockIdx.x;                  // 0..3
  int slice = blockIdx.y * blockDim.y + threadIdx.y;   // 0..15
  float w0 = t_cw[u], w1 = t_cw[128+u], w2 = t_cw[256+u];
  float cb = t_cb[u];
  float sc = __fmul_rn(BN_RS, t_g1[u]);
  float b1 = t_b1[u];
  float mx = -INFINITY;
  const float* P = pts + ((size_t)b*2048 + (size_t)slice*128)*3;
  for (int n = 0; n < 128; ++n){
    float y = __fadd_rn(__fadd_rn(__fmul_rn(P[n*3+0], w0), __fmul_rn(P[n*3+1], w1)),
                        __fmul_rn(P[n*3+2], w2));
    y = __fadd_rn(y, cb);
    y = __fadd_rn(__fmul_rn(y, sc), b1);
    mx = fmaxf(mx, silu_f64(y));
  }
  atomicMax(&xm_mono[b*128+u], f2mono(mx));
}

// ---------------- T-Net stage 2 (f64 accum) ----------------
__global__ void tnet2_kernel(const unsigned* __restrict__ xm_mono,
                             const float* __restrict__ d1w, const float* __restrict__ d1b,
                             const float* __restrict__ g2, const float* __restrict__ b2,
                             const float* __restrict__ d2w, const float* __restrict__ d2b,
                             float* __restrict__ T9){
  __shared__ float xs[128], x2s[128];
  int u = threadIdx.x, b = blockIdx.x;
  xs[u] = mono2f(xm_mono[b*128+u]);
  __syncthreads();
  double acc = (double)d1b[u];
  for (int v = 0; v < 128; ++v) acc += (double)xs[v] * (double)d1w[v*128+u];
  double sc = (double)__fmul_rn(BN_RS, g2[u]);
  acc = acc*sc + (double)b2[u];
  double e = exp(-acc);
  x2s[u] = (float)(acc / (1.0 + e));
  __syncthreads();
  if (u < 9){
    double t = (double)d2b[u];
    for (int v = 0; v < 128; ++v) t += (double)x2s[v] * (double)d2w[v*9+u];
    T9[b*9+u] = (float)t;
  }
}

// ---------------- pc = pts @ T (np order, no fma) + sq ----------------
__global__ void pc_kernel(const float* __restrict__ pts, const float* __restrict__ T9,
                          float4* __restrict__ pc4){
  int i = blockIdx.x*blockDim.x + threadIdx.x;   // 0..8191
  int b = i >> 11;
  const float* p = pts + (size_t)i*3;
  float x = p[0], y = p[1], z = p[2];
  const float* T = T9 + b*9;
  float px = __fadd_rn(__fadd_rn(__fmul_rn(x, T[0]), __fmul_rn(y, T[3])), __fmul_rn(z, T[6]));
  float py = __fadd_rn(__fadd_rn(__fmul_rn(x, T[1]), __fmul_rn(y, T[4])), __fmul_rn(z, T[7]));
  float pz = __fadd_rn(__fadd_rn(__fmul_rn(x, T[2]), __fmul_rn(y, T[5])), __fmul_rn(z, T[8]));
  float sq = __fadd_rn(__fadd_rn(__fmul_rn(px, px), __fmul_rn(py, py)), __fmul_rn(pz, pz));
  pc4[i] = make_float4(px, py, pz, sq);
}

// ---------------- grouping ----------------
__global__ __launch_bounds__(256) void group_kernel(const float4* __restrict__ pc4,
                                                    f16* __restrict__ f9){
  __shared__ float4 pcl[2048];
  __shared__ int ones[4][3][32];
  __shared__ int zer [4][3][32];
  const float RAD[3] = {0.1f, 0.3f, 0.5f};
  int tid = threadIdx.x, wave = tid >> 6, lane = tid & 63;
  int bid = blockIdx.x;
  int b = bid >> 9, n0 = (bid & 511) * 4;
  const float4* src = pc4 + (size_t)b*2048;
  for (int x = tid; x < 2048; x += 256) pcl[x] = src[x];
  __syncthreads();

  int n = n0 + wave;
  float4 pi = pcl[n];
  float xi = pi.x, yi = pi.y, zi = pi.z, sqi = pi.w;
  int c1[3] = {0,0,0}, c0[3] = {0,0,0};
  unsigned long long lt = (1ULL << lane) - 1ULL;

  for (int ch = 0; ch < 32; ++ch){
    int j = ch*64 + lane;
    float4 pj = pcl[j];
    float dot = __fadd_rn(__fadd_rn(__fmul_rn(xi, pj.x), __fmul_rn(yi, pj.y)),
                          __fmul_rn(zi, pj.z));
    float d2 = __fsub_rn(__fadd_rn(sqi, pj.w), __fmul_rn(2.f, dot));
    float dist = sqrtf(fmaxf(d2, 0.f));
    #pragma unroll
    for (int ri = 0; ri < 3; ++ri){
      bool in = (dist <= RAD[ri]);
      unsigned long long m = __ballot(in);
      int pc_lt = (int)__popcll(m & lt);
      if (c1[ri] < 32){
        int pos = c1[ri] + pc_lt;
        if (in && pos < 32) ones[wave][ri][pos] = j;
      }
      if (c0[ri] < 32){
        int pos = c0[ri] + (int)(lane - pc_lt);
        if (!in && pos < 32) zer[wave][ri][pos] = j;
      }
      int t1 = (int)__popcll(m);
      c1[ri] += t1;
      c0[ri] += 64 - t1;
    }
    if (c1[0] >= 32 && c1[1] >= 32 && c1[2] >= 32 &&
        c0[0] >= 32 && c0[1] >= 32 && c0[2] >= 32) break;
  }
  __syncthreads();

  if (lane < 32){
    h8v va, vb;
    #pragma unroll
    for (int t = 0; t < 8; ++t){ va[t] = (f16)0.f; vb[t] = (f16)0.f; }
    #pragma unroll
    for (int ri = 0; ri < 3; ++ri){
      int cc = c1[ri] < 32 ? c1[ri] : 32;
      int sel = (lane < cc) ? ones[wave][ri][lane] : zer[wave][ri][lane - cc];
      float4 p = pcl[sel];
      if (ri == 0){ va[0]=(f16)p.x; va[1]=(f16)p.y; va[2]=(f16)p.z; }
      if (ri == 1){ va[3]=(f16)p.x; va[4]=(f16)p.y; va[5]=(f16)p.z; }
      if (ri == 2){ va[6]=(f16)p.x; va[7]=(f16)p.y; vb[0]=(f16)p.z; }
    }
    f16* dst = f9 + (((size_t)(b*2048 + n) * 32 + lane) << 4);
    *(h8v*)dst = va;
    *(h8v*)(dst + 8) = vb;
  }
}

// ---------------- weight prep: transpose + f16, layout [co][ci] ----------------
__global__ void prep_kernel(const float* __restrict__ c1w, const float* __restrict__ resw,
                            const float* __restrict__ b0w, const float* __restrict__ b1w,
                            const float* __restrict__ b2w,
                            f16* __restrict__ c1t, f16* __restrict__ resT, f16* __restrict__ b0T,
                            f16* __restrict__ b1T, f16* __restrict__ b2T){
  int i0 = blockIdx.x*blockDim.x + threadIdx.x;
  int stride = gridDim.x*blockDim.x;
  for (int x = i0; x < 512*32;  x += stride){ int co=x>>5, ci=x&31;  c1t[x] = (f16)(ci<9 ? c1w[ci*512+co] : 0.f); }
  for (int x = i0; x < 512*512; x += stride){ int co=x>>9, ci=x&511; resT[x]= (f16)resw[ci*512+co]; }
  for (int x = i0; x < 512*512; x += stride){ int co=x>>9, ci=x&511; b0T[x] = (f16)b0w[ci*512+co]; }
  for (int x = i0; x < 256*512; x += stride){ int co=x>>9, ci=x&511; b1T[x] = (f16)b1w[ci*256+co]; }
  for (int x = i0; x < 176*256; x += stride){ int co=x>>8, ci=x&255; b2T[x] = (f16)(co<170 ? b2w[ci*170+co] : 0.f); }
}

// ---------------- MLP ----------------
// act tile: 64 rows x 512 f16, stride 1024 B, XOR-swizzled by ((row&7)<<4)
__device__ __forceinline__ int swzb(int row, int c){
  return (row*1024 + c*2) ^ ((row & 7) << 4);
}
// weight tile: row s (=ch>>4) is 1024B; data W[ch][t*32 + jc*8 ..+7] lives at
// byte s*1024 + jc*256 + (ch&15)*16  -> a wave reading (ct fixed) is lane*16 linear.
__device__ __forceinline__ int woff(int ch, int lkg){
  return ((ch >> 4) << 10) + (lkg << 8) + ((ch & 15) << 4);
}

// async-stage one CO x 32ci weight tile; DMA writes wtile+s*512 + lane*16 (linear),
// per-lane source picks (channel = s*16 + lane&15, k-chunk = lane>>4).
template<int CO, int CI>
__device__ __forceinline__ void stage_w(const f16* __restrict__ wt, f16* wtile,
                                        int t, int wave, int lane){
  const int jc = lane >> 4, chl = lane & 15;
  const f16* src0 = wt + (size_t)chl*CI + t*32 + jc*8;
  for (int s = wave; s < CO/16; s += 8){
    __builtin_amdgcn_global_load_lds(AS1c(src0 + (size_t)s*16*CI),
                                     AS3(wtile + s*512), 16, 0, 0);
  }
}

// swapped-operand step: acc[mt][ct] += W(16ch x 32k) * A(32k x 16rows)
template<int NCT>
__device__ __forceinline__ void mm_step_swp(const char* actc, const char* wtc,
                                            int co0, int lrow, int lkg, int t,
                                            f32x4 (&acc)[4][NCT]){
  const int xr = (lrow & 7) << 4;
  h8v a[4];
  int koff = ((t*4 + lkg) << 4) ^ xr;
  #pragma unroll
  for (int mt = 0; mt < 4; ++mt)
    a[mt] = *(const h8v*)(actc + (mt*16 + lrow)*1024 + koff);
  #pragma unroll
  for (int ct = 0; ct < NCT; ++ct){
    int ch = co0 + ct*16 + lrow;
    h8v w = *(const h8v*)(wtc + woff(ch, lkg));
    #pragma unroll
    for (int mt = 0; mt < 4; ++mt)
      acc[mt][ct] = __builtin_amdgcn_mfma_f32_16x16x32_f16(w, a[mt], acc[mt][ct], 0, 0, 0);
  }
}

// depth-2 pipelined layer: 3 weight buffers, counted vmcnt, raw barriers.
// DM = own-wave DMA instructions per stage (CO/16/8).
template<int CO, int CI, int NCT, int DM>
__device__ __forceinline__ void run_layer(const f16* __restrict__ WT, const char* bufc,
                                          f16* wb0, f16* wb1, f16* wb2, int co0,
                                          int wave, int lane, int lrow, int lkg,
                                          f32x4 (&acc)[4][NCT]){
  constexpr int NT = CI/32;
  f16* wb[3] = {wb0, wb1, wb2};
  stage_w<CO,CI>(WT, wb0, 0, wave, lane);
  stage_w<CO,CI>(WT, wb1, 1, wave, lane);
  asm volatile("s_waitcnt vmcnt(%0)" :: "n"(DM) : "memory");   // tile0 resident (own)
  __builtin_amdgcn_s_barrier();                                 // all waves' tile0 in
  #pragma unroll
  for (int t = 0; t < NT; ++t){
    if (t + 2 < NT) stage_w<CO,CI>(WT, wb[(t+2)%3], t+2, wave, lane);
    mm_step_swp<NCT>(bufc, (const char*)wb[t%3], co0, lrow, lkg, t, acc);
    if (t + 1 < NT){
      if (t + 2 < NT) asm volatile("s_waitcnt vmcnt(%0)" :: "n"(DM) : "memory");
      else            asm volatile("s_waitcnt vmcnt(0)" ::: "memory");
      __builtin_amdgcn_s_barrier();                             // tile t+1 ready
    }
  }
  __syncthreads();   // all reads of acts + wtiles done; safe to overwrite acts
}

// packed epilogue: lane writes 4 consecutive channels of one row as one 8B store
template<int NCT>
__device__ __forceinline__ void epi_swp(char* bufc, int co0,
    const float* __restrict__ g, const float* __restrict__ bv, const float* __restrict__ bt,
    int lrow, int lkg, f32x4 (&acc)[4][NCT]){
  #pragma unroll
  for (int ct = 0; ct < NCT; ++ct){
    int co = co0 + ct*16 + lkg*4;
    float4 g4 = *(const float4*)(g + co);
    float4 b4 = *(const float4*)(bv + co);
    float4 t4 = *(const float4*)(bt + co);
    float sc0 = BN_RS*g4.x, sc1 = BN_RS*g4.y, sc2 = BN_RS*g4.z, sc3 = BN_RS*g4.w;
    float bb0 = b4.x*sc0 + t4.x, bb1 = b4.y*sc1 + t4.y;
    float bb2 = b4.z*sc2 + t4.z, bb3 = b4.w*sc3 + t4.w;
    #pragma unroll
    for (int mt = 0; mt < 4; ++mt){
      int r = mt*16 + lrow;
      h4v h;
      h[0] = (f16)silu_fast(acc[mt][ct][0]*sc0 + bb0);
      h[1] = (f16)silu_fast(acc[mt][ct][1]*sc1 + bb1);
      h[2] = (f16)silu_fast(acc[mt][ct][2]*sc2 + bb2);
      h[3] = (f16)silu_fast(acc[mt][ct][3]*sc3 + bb3);
      *(h4v*)(bufc + swzb(r, co)) = h;
    }
  }
}

__global__ __launch_bounds__(512) void mlp_kernel(
    const f16* __restrict__ f9,
    const f16* __restrict__ c1t, const f16* __restrict__ resT,
    const f16* __restrict__ b0T, const f16* __restrict__ b1T, const f16* __restrict__ b2T,
    const float* __restrict__ c1_b, const float* __restrict__ c1_g, const float* __restrict__ c1_be,
    const float* __restrict__ res_b,
    const float* __restrict__ b0_b, const float* __restrict__ b0_g, const float* __restrict__ b0_be,
    const float* __restrict__ b1_b, const float* __restrict__ b1_g, const float* __restrict__ b1_be,
    const float* __restrict__ b2_b, const float* __restrict__ b2_g, const float* __restrict__ b2_be,
    unsigned* __restrict__ outmax){
  __shared__ __align__(16) f16 buf[64*512];       // 64 KiB acts, in-place
  __shared__ __align__(16) f16 wbuf[3][16384];    // 3 x 32 KiB weight tiles (DMA pipeline)
  char* bufc = (char*)buf;
  const int tid  = threadIdx.x;
  const int wave = tid >> 6, lane = tid & 63;
  const int lrow = lane & 15, lkg = lane >> 4;
  const int bid = blockIdx.x;
  const int b = bid >> 10, k = (bid >> 5) & 31, n0 = (bid & 31) << 6;

  // stage f9 rows [64][32] into buf front region (cols 16..31 zero)
  if (tid < 256){
    int row = tid >> 2, part = tid & 3;
    h8v v;
    if (part < 2){
      const f16* src = f9 + (((size_t)(b*2048 + n0 + row) * 32 + k) << 4) + part*8;
      v = *(const h8v*)src;
    } else {
      #pragma unroll
      for (int t = 0; t < 8; ++t) v[t] = (f16)0.f;
    }
    *(h8v*)&buf[row*32 + part*8] = v;
  }

  const f32x4 zf = {0.f, 0.f, 0.f, 0.f};
  f32x4 acc4[4][4];

  // ---- layer 1: Ci=32 (padded 9), Co=512, acts from packed [64][32] region ----
  stage_w<512, 32>(c1t, wbuf[0], 0, wave, lane);
  asm volatile("s_waitcnt vmcnt(0)" ::: "memory");
  __syncthreads();                                 // f9 staged + w tile ready
  #pragma unroll
  for (int mt = 0; mt < 4; ++mt)
    #pragma unroll
    for (int ct = 0; ct < 4; ++ct) acc4[mt][ct] = zf;
  {
    h8v a[4];
    #pragma unroll
    for (int mt = 0; mt < 4; ++mt)
      a[mt] = *(const h8v*)&buf[(mt*16 + lrow)*32 + lkg*8];
    #pragma unroll
    for (int ct = 0; ct < 4; ++ct){
      int ch = wave*64 + ct*16 + lrow;
      h8v w = *(const h8v*)((const char*)wbuf[0] + woff(ch, lkg));
      #pragma unroll
      for (int mt = 0; mt < 4; ++mt)
        acc4[mt][ct] = __builtin_amdgcn_mfma_f32_16x16x32_f16(w, a[mt], acc4[mt][ct], 0, 0, 0);
    }
  }
  __syncthreads();                                 // reads of staged f9 done
  epi_swp<4>(bufc, wave*64, c1_g, c1_b, c1_be, lrow, lkg, acc4);
  __syncthreads();

  // ---- residual: f = h1 + (h1 @ res_w + res_b), in-place ----
  #pragma unroll
  for (int mt = 0; mt < 4; ++mt)
    #pragma unroll
    for (int ct = 0; ct < 4; ++ct) acc4[mt][ct] = zf;
  run_layer<512, 512, 4, 4>(resT, bufc, wbuf[0], wbuf[1], wbuf[2], wave*64, wave, lane, lrow, lkg, acc4);
  #pragma unroll
  for (int ct = 0; ct < 4; ++ct){
    int co = wave*64 + ct*16 + lkg*4;
    float4 rb4 = *(const float4*)(res_b + co);
    #pragma unroll
    for (int mt = 0; mt < 4; ++mt){
      int r = mt*16 + lrow;
      h4v* p = (h4v*)(bufc + swzb(r, co));        // lane-self-owned location
      h4v h = *p;
      h4v o;
      o[0] = (f16)((float)h[0] + acc4[mt][ct][0] + rb4.x);
      o[1] = (f16)((float)h[1] + acc4[mt][ct][1] + rb4.y);
      o[2] = (f16)((float)h[2] + acc4[mt][ct][2] + rb4.z);
      o[3] = (f16)((float)h[3] + acc4[mt][ct][3] + rb4.w);
      *p = o;
    }
  }
  __syncthreads();

  // ---- blk0: 512 -> 512, in-place ----
  #pragma unroll
  for (int mt = 0; mt < 4; ++mt)
    #pragma unroll
    for (int ct = 0; ct < 4; ++ct) acc4[mt][ct] = zf;
  run_layer<512, 512, 4, 4>(b0T, bufc, wbuf[0], wbuf[1], wbuf[2], wave*64, wave, lane, lrow, lkg, acc4);
  epi_swp<4>(bufc, wave*64, b0_g, b0_b, b0_be, lrow, lkg, acc4);
  __syncthreads();

  // ---- blk1: 512 -> 256, in-place (cols 0..255) ----
  f32x4 acc2[4][2];
  #pragma unroll
  for (int mt = 0; mt < 4; ++mt){ acc2[mt][0] = zf; acc2[mt][1] = zf; }
  run_layer<256, 512, 2, 2>(b1T, bufc, wbuf[0], wbuf[1], wbuf[2], wave*32, wave, lane, lrow, lkg, acc2);
  epi_swp<2>(bufc, wave*32, b1_g, b1_b, b1_be, lrow, lkg, acc2);
  __syncthreads();

  // ---- blk2: 256 -> 170 (pad 176), acts as A-operand, + row-max + atomic ----
  f32x4 acc3[4][2];
  #pragma unroll
  for (int mt = 0; mt < 4; ++mt){ acc3[mt][0] = zf; acc3[mt][1] = zf; }
  {
    const int xr = (lrow & 7) << 4;
    const bool has2 = (wave + 8) < 11;
    stage_w<176, 256>(b2T, wbuf[0], 0, wave, lane);
    asm volatile("s_waitcnt vmcnt(0)" ::: "memory");
    __syncthreads();
    #pragma unroll
    for (int t = 0; t < 8; ++t){
      f16* cur = (t & 1) ? wbuf[1] : wbuf[0];
      f16* nxt = (t & 1) ? wbuf[0] : wbuf[1];
      if (t + 1 < 8) stage_w<176, 256>(b2T, nxt, t+1, wave, lane);
      h8v a[4];
      int koff = ((t*4 + lkg) << 4) ^ xr;
      #pragma unroll
      for (int mt = 0; mt < 4; ++mt)
        a[mt] = *(const h8v*)(bufc + (mt*16 + lrow)*1024 + koff);
      {
        int ch = wave*16 + lrow;
        h8v w = *(const h8v*)((const char*)cur + woff(ch, lkg));
        #pragma unroll
        for (int mt = 0; mt < 4; ++mt)
          acc3[mt][0] = __builtin_amdgcn_mfma_f32_16x16x32_f16(a[mt], w, acc3[mt][0], 0, 0, 0);
      }
      if (has2){
        int ch = (wave + 8)*16 + lrow;
        h8v w = *(const h8v*)((const char*)cur + woff(ch, lkg));
        #pragma unroll
        for (int mt = 0; mt < 4; ++mt)
          acc3[mt][1] = __builtin_amdgcn_mfma_f32_16x16x32_f16(a[mt], w, acc3[mt][1], 0, 0, 0);
      }
      if (t + 1 < 8){
        asm volatile("s_waitcnt vmcnt(0)" ::: "memory");
        __syncthreads();
      }
    }
    #pragma unroll
    for (int t = 0; t < 2; ++t){
      if (t == 1 && !has2) break;
      int c = ((t == 0) ? wave : wave + 8)*16 + lrow;
      if (c < 170){
        float sc = BN_RS * b2_g[c];
        float bb = b2_b[c]*sc + b2_be[c];
        float mx = -INFINITY;
        #pragma unroll
        for (int mt = 0; mt < 4; ++mt)
          #pragma unroll
          for (int rg = 0; rg < 4; ++rg)
            mx = fmaxf(mx, silu_fast(acc3[mt][t][rg]*sc + bb));
        mx = fmaxf(mx, __shfl_xor(mx, 16));
        mx = fmaxf(mx, __shfl_xor(mx, 32));
        if (lkg == 0)
          atomicMax(&outmax[b*5440 + k*170 + c], f2mono(mx));
      }
    }
  }
}

__global__ void finalize_kernel(const unsigned* __restrict__ m, float* __restrict__ out, int n){
  int i = blockIdx.x*blockDim.x + threadIdx.x;
  if (i < n) out[i] = mono2f(m[i]);
}

// ---------------- launch ----------------
extern "C" void kernel_launch(void* const* d_in, const int* in_sizes, int n_in,
                              void* d_out, int out_size, void* d_ws, size_t ws_size,
                              hipStream_t stream){
  const float* pts    = (const float*)d_in[0];
  const float* t_cw   = (const float*)d_in[1];
  const float* t_cb   = (const float*)d_in[2];
  const float* t_g1   = (const float*)d_in[3];
  const float* t_b1   = (const float*)d_in[4];
  const float* t_d1w  = (const float*)d_in[5];
  const float* t_d1b  = (const float*)d_in[6];
  const float* t_g2   = (const float*)d_in[7];
  const float* t_b2   = (const float*)d_in[8];
  const float* t_d2w  = (const float*)d_in[9];
  const float* t_d2b  = (const float*)d_in[10];
  const float* c1_w   = (const float*)d_in[11];
  const float* c1_b   = (const float*)d_in[12];
  const float* c1_g   = (const float*)d_in[13];
  const float* c1_be  = (const float*)d_in[14];
  const float* res_w  = (const float*)d_in[15];
  const float* res_b  = (const float*)d_in[16];
  const float* b0_w   = (const float*)d_in[17];
  const float* b0_b   = (const float*)d_in[18];
  const float* b0_g   = (const float*)d_in[19];
  const float* b0_be  = (const float*)d_in[20];
  const float* b1_w   = (const float*)d_in[21];
  const float* b1_b   = (const float*)d_in[22];
  const float* b1_g   = (const float*)d_in[23];
  const float* b1_be  = (const float*)d_in[24];
  const float* b2_w   = (const float*)d_in[25];
  const float* b2_b   = (const float*)d_in[26];
  const float* b2_g   = (const float*)d_in[27];
  const float* b2_be  = (const float*)d_in[28];

  char* ws = (char*)d_ws;
  float*    T9   = (float*)(ws + OFF_T9);
  unsigned* XM   = (unsigned*)(ws + OFF_XM);
  float4*   PC4  = (float4*)(ws + OFF_PC4);
  unsigned* OUTM = (unsigned*)(ws + OFF_OUT);
  f16* C1T  = (f16*)(ws + OFF_C1T);
  f16* REST = (f16*)(ws + OFF_REST);
  f16* B0T  = (f16*)(ws + OFF_B0T);
  f16* B1T  = (f16*)(ws + OFF_B1T);
  f16* B2T  = (f16*)(ws + OFF_B2T);
  f16* F9   = (f16*)(ws + OFF_F9);

  hipMemsetAsync(ws + OFF_XM, 0, 4*128*4, stream);
  hipMemsetAsync(ws + OFF_OUT, 0, 21760*4, stream);

  prep_kernel<<<512, 256, 0, stream>>>(c1_w, res_w, b0_w, b1_w, b2_w, C1T, REST, B0T, B1T, B2T);
  tnet1_kernel<<<dim3(4,4), dim3(128,4), 0, stream>>>(pts, t_cw, t_cb, t_g1, t_b1, XM);
  tnet2_kernel<<<4, 128, 0, stream>>>(XM, t_d1w, t_d1b, t_g2, t_b2, t_d2w, t_d2b, T9);
  pc_kernel<<<32, 256, 0, stream>>>(pts, T9, PC4);
  group_kernel<<<2048, 256, 0, stream>>>(PC4, F9);
  mlp_kernel<<<4096, 512, 0, stream>>>(F9, C1T, REST, B0T, B1T, B2T,
                                       c1_b, c1_g, c1_be, res_b,
                                       b0_b, b0_g, b0_be,
                                       b1_b, b1_g, b1_be,
                                       b2_b, b2_g, b2_be, OUTM);
  finalize_kernel<<<(out_size + 255)/256, 256, 0, stream>>>(OUTM, (float*)d_out, out_size);
}

// Round 7
// 1054.809 us; speedup vs baseline: 1.0902x; 1.0902x over previous
//
#include <hip/hip_runtime.h>
#include <math.h>

#define BN_RS 0.9995003746877732f

typedef unsigned short u16;
typedef _Float16 f16;
typedef __attribute__((ext_vector_type(8))) _Float16 h8v;     // 8 f16 (A/B frag)
typedef __attribute__((ext_vector_type(4))) _Float16 h4v;     // packed 4 f16 (8B)
typedef __attribute__((ext_vector_type(4))) float f32x4;      // C/D frag

#define AS1c(p) ((const __attribute__((address_space(1))) void*)(p))
#define AS3(p)  ((__attribute__((address_space(3))) void*)(p))

// ---------------- helpers ----------------
__device__ __forceinline__ unsigned f2mono(float f){
  unsigned u = __float_as_uint(f);
  return (u & 0x80000000u) ? ~u : (u | 0x80000000u);
}
__device__ __forceinline__ float mono2f(unsigned m){
  unsigned u = (m & 0x80000000u) ? (m & 0x7FFFFFFFu) : ~m;
  return __uint_as_float(u);
}
__device__ __forceinline__ float silu_fast(float x){ return x / (1.f + __expf(-x)); }
__device__ __forceinline__ float silu_f64(float x){
  double e = exp(-(double)x);
  return (float)((double)x / (1.0 + e));
}

// ---------------- ws layout (bytes) ----------------
constexpr size_t OFF_T9   = 0;         //  4*9*4
constexpr size_t OFF_XM   = 1024;      //  4*128*4 (mono uints)
constexpr size_t OFF_PC4  = 4096;      //  8192*16
constexpr size_t OFF_OUT  = 139264;    //  21760*4
constexpr size_t OFF_C1T  = 227328;    //  512*32*2
constexpr size_t OFF_REST = 262144;    //  512*512*2
constexpr size_t OFF_B0T  = 786432;    //  512*512*2
constexpr size_t OFF_B1T  = 1310720;   //  256*512*2
constexpr size_t OFF_B2T  = 1572864;   //  176*256*2
constexpr size_t OFF_F9   = 1703936;   //  8192*32*16*2

// ---------------- T-Net stage 1 ----------------
__global__ void tnet1_kernel(const float* __restrict__ pts, const float* __restrict__ t_cw,
                             const float* __restrict__ t_cb, const float* __restrict__ t_g1,
                             const float* __restrict__ t_b1, unsigned* __restrict__ xm_mono){
  int u = threadIdx.x;                 // 0..127
  int b = blockIdx.x;                  // 0..3
  int slice = blockIdx.y * blockDim.y + threadIdx.y;   // 0..15
  float w0 = t_cw[u], w1 = t_cw[128+u], w2 = t_cw[256+u];
  float cb = t_cb[u];
  float sc = __fmul_rn(BN_RS, t_g1[u]);
  float b1 = t_b1[u];
  float mx = -INFINITY;
  const float* P = pts + ((size_t)b*2048 + (size_t)slice*128)*3;
  for (int n = 0; n < 128; ++n){
    float y = __fadd_rn(__fadd_rn(__fmul_rn(P[n*3+0], w0), __fmul_rn(P[n*3+1], w1)),
                        __fmul_rn(P[n*3+2], w2));
    y = __fadd_rn(y, cb);
    y = __fadd_rn(__fmul_rn(y, sc), b1);
    mx = fmaxf(mx, silu_f64(y));
  }
  atomicMax(&xm_mono[b*128+u], f2mono(mx));
}

// ---------------- T-Net stage 2 (f64 accum) ----------------
__global__ void tnet2_kernel(const unsigned* __restrict__ xm_mono,
                             const float* __restrict__ d1w, const float* __restrict__ d1b,
                             const float* __restrict__ g2, const float* __restrict__ b2,
                             const float* __restrict__ d2w, const float* __restrict__ d2b,
                             float* __restrict__ T9){
  __shared__ float xs[128], x2s[128];
  int u = threadIdx.x, b = blockIdx.x;
  xs[u] = mono2f(xm_mono[b*128+u]);
  __syncthreads();
  double acc = (double)d1b[u];
  for (int v = 0; v < 128; ++v) acc += (double)xs[v] * (double)d1w[v*128+u];
  double sc = (double)__fmul_rn(BN_RS, g2[u]);
  acc = acc*sc + (double)b2[u];
  double e = exp(-acc);
  x2s[u] = (float)(acc / (1.0 + e));
  __syncthreads();
  if (u < 9){
    double t = (double)d2b[u];
    for (int v = 0; v < 128; ++v) t += (double)x2s[v] * (double)d2w[v*9+u];
    T9[b*9+u] = (float)t;
  }
}

// ---------------- pc = pts @ T (np order, no fma) + sq ----------------
__global__ void pc_kernel(const float* __restrict__ pts, const float* __restrict__ T9,
                          float4* __restrict__ pc4){
  int i = blockIdx.x*blockDim.x + threadIdx.x;   // 0..8191
  int b = i >> 11;
  const float* p = pts + (size_t)i*3;
  float x = p[0], y = p[1], z = p[2];
  const float* T = T9 + b*9;
  float px = __fadd_rn(__fadd_rn(__fmul_rn(x, T[0]), __fmul_rn(y, T[3])), __fmul_rn(z, T[6]));
  float py = __fadd_rn(__fadd_rn(__fmul_rn(x, T[1]), __fmul_rn(y, T[4])), __fmul_rn(z, T[7]));
  float pz = __fadd_rn(__fadd_rn(__fmul_rn(x, T[2]), __fmul_rn(y, T[5])), __fmul_rn(z, T[8]));
  float sq = __fadd_rn(__fadd_rn(__fmul_rn(px, px), __fmul_rn(py, py)), __fmul_rn(pz, pz));
  pc4[i] = make_float4(px, py, pz, sq);
}

// ---------------- grouping ----------------
__global__ __launch_bounds__(256) void group_kernel(const float4* __restrict__ pc4,
                                                    f16* __restrict__ f9){
  __shared__ float4 pcl[2048];
  __shared__ int ones[4][3][32];
  __shared__ int zer [4][3][32];
  const float RAD[3] = {0.1f, 0.3f, 0.5f};
  int tid = threadIdx.x, wave = tid >> 6, lane = tid & 63;
  int bid = blockIdx.x;
  int b = bid >> 9, n0 = (bid & 511) * 4;
  const float4* src = pc4 + (size_t)b*2048;
  for (int x = tid; x < 2048; x += 256) pcl[x] = src[x];
  __syncthreads();

  int n = n0 + wave;
  float4 pi = pcl[n];
  float xi = pi.x, yi = pi.y, zi = pi.z, sqi = pi.w;
  int c1[3] = {0,0,0}, c0[3] = {0,0,0};
  unsigned long long lt = (1ULL << lane) - 1ULL;

  for (int ch = 0; ch < 32; ++ch){
    int j = ch*64 + lane;
    float4 pj = pcl[j];
    float dot = __fadd_rn(__fadd_rn(__fmul_rn(xi, pj.x), __fmul_rn(yi, pj.y)),
                          __fmul_rn(zi, pj.z));
    float d2 = __fsub_rn(__fadd_rn(sqi, pj.w), __fmul_rn(2.f, dot));
    float dist = sqrtf(fmaxf(d2, 0.f));
    #pragma unroll
    for (int ri = 0; ri < 3; ++ri){
      bool in = (dist <= RAD[ri]);
      unsigned long long m = __ballot(in);
      int pc_lt = (int)__popcll(m & lt);
      if (c1[ri] < 32){
        int pos = c1[ri] + pc_lt;
        if (in && pos < 32) ones[wave][ri][pos] = j;
      }
      if (c0[ri] < 32){
        int pos = c0[ri] + (int)(lane - pc_lt);
        if (!in && pos < 32) zer[wave][ri][pos] = j;
      }
      int t1 = (int)__popcll(m);
      c1[ri] += t1;
      c0[ri] += 64 - t1;
    }
    if (c1[0] >= 32 && c1[1] >= 32 && c1[2] >= 32 &&
        c0[0] >= 32 && c0[1] >= 32 && c0[2] >= 32) break;
  }
  __syncthreads();

  if (lane < 32){
    h8v va, vb;
    #pragma unroll
    for (int t = 0; t < 8; ++t){ va[t] = (f16)0.f; vb[t] = (f16)0.f; }
    #pragma unroll
    for (int ri = 0; ri < 3; ++ri){
      int cc = c1[ri] < 32 ? c1[ri] : 32;
      int sel = (lane < cc) ? ones[wave][ri][lane] : zer[wave][ri][lane - cc];
      float4 p = pcl[sel];
      if (ri == 0){ va[0]=(f16)p.x; va[1]=(f16)p.y; va[2]=(f16)p.z; }
      if (ri == 1){ va[3]=(f16)p.x; va[4]=(f16)p.y; va[5]=(f16)p.z; }
      if (ri == 2){ va[6]=(f16)p.x; va[7]=(f16)p.y; vb[0]=(f16)p.z; }
    }
    f16* dst = f9 + (((size_t)(b*2048 + n) * 32 + lane) << 4);
    *(h8v*)dst = va;
    *(h8v*)(dst + 8) = vb;
  }
}

// ---------------- weight prep: transpose + f16, layout [co][ci] ----------------
__global__ void prep_kernel(const float* __restrict__ c1w, const float* __restrict__ resw,
                            const float* __restrict__ b0w, const float* __restrict__ b1w,
                            const float* __restrict__ b2w,
                            f16* __restrict__ c1t, f16* __restrict__ resT, f16* __restrict__ b0T,
                            f16* __restrict__ b1T, f16* __restrict__ b2T){
  int i0 = blockIdx.x*blockDim.x + threadIdx.x;
  int stride = gridDim.x*blockDim.x;
  for (int x = i0; x < 512*32;  x += stride){ int co=x>>5, ci=x&31;  c1t[x] = (f16)(ci<9 ? c1w[ci*512+co] : 0.f); }
  for (int x = i0; x < 512*512; x += stride){ int co=x>>9, ci=x&511; resT[x]= (f16)resw[ci*512+co]; }
  for (int x = i0; x < 512*512; x += stride){ int co=x>>9, ci=x&511; b0T[x] = (f16)b0w[ci*512+co]; }
  for (int x = i0; x < 256*512; x += stride){ int co=x>>9, ci=x&511; b1T[x] = (f16)b1w[ci*256+co]; }
  for (int x = i0; x < 176*256; x += stride){ int co=x>>8, ci=x&255; b2T[x] = (f16)(co<170 ? b2w[ci*170+co] : 0.f); }
}

// ---------------- MLP ----------------
// act tile: 64 rows x 512 f16, stride 1024 B, XOR-swizzled by ((row&7)<<4)
__device__ __forceinline__ int swzb(int row, int c){
  return (row*1024 + c*2) ^ ((row & 7) << 4);
}
// weight tile: row s (=ch>>4) is 1024B; W[ch][t*32 + jc*8 ..] at byte
// s*1024 + jc*256 + (ch&15)*16 -> a wave reading (ct fixed) is lane*16 linear (conflict-free).
__device__ __forceinline__ int woff(int ch, int lkg){
  return ((ch >> 4) << 10) + (lkg << 8) + ((ch & 15) << 4);
}

// 16-wave stage of one CO x 32ci weight tile; DMA dest = wtile + s*512 + lane*16 (linear),
// per-lane source picks (channel = s*16 + lane&15, k-chunk = lane>>4).
template<int CO, int CI>
__device__ __forceinline__ void stage16(const f16* __restrict__ wt, f16* wtile,
                                        int t, int wave, int lane){
  const int jc = lane >> 4, chl = lane & 15;
  const f16* src0 = wt + (size_t)chl*CI + t*32 + jc*8;
  for (int s = wave; s < CO/16; s += 16){
    __builtin_amdgcn_global_load_lds(AS1c(src0 + (size_t)s*16*CI),
                                     AS3(wtile + s*512), 16, 0, 0);
  }
}

// swapped-operand step: acc[mt][ct] += W(16ch x 32k) * A(32k x 16rows)
template<int NCT>
__device__ __forceinline__ void mm_step_swp(const char* actc, const char* wtc,
                                            int co0, int lrow, int lkg, int t,
                                            f32x4 (&acc)[4][NCT]){
  const int xr = (lrow & 7) << 4;
  h8v a[4];
  int koff = ((t*4 + lkg) << 4) ^ xr;
  #pragma unroll
  for (int mt = 0; mt < 4; ++mt)
    a[mt] = *(const h8v*)(actc + (mt*16 + lrow)*1024 + koff);
  #pragma unroll
  for (int ct = 0; ct < NCT; ++ct){
    int ch = co0 + ct*16 + lrow;
    h8v w = *(const h8v*)(wtc + woff(ch, lkg));
    #pragma unroll
    for (int mt = 0; mt < 4; ++mt)
      acc[mt][ct] = __builtin_amdgcn_mfma_f32_16x16x32_f16(w, a[mt], acc[mt][ct], 0, 0, 0);
  }
}

// shared-weight layer: stage tile t (all 16 waves) -> sync -> compute -> sync
template<int CO, int CI, int NCT>
__device__ __forceinline__ void run_layer_sh(const f16* __restrict__ WT, const char* actc,
                                             f16* wb, int co0,
                                             int wave, int lane, int lrow, int lkg,
                                             f32x4 (&acc)[4][NCT]){
  #pragma unroll
  for (int t = 0; t < CI/32; ++t){
    stage16<CO,CI>(WT, wb, t, wave, lane);
    __syncthreads();                      // DMA drained -> tile t ready
    mm_step_swp<NCT>(actc, (const char*)wb, co0, lrow, lkg, t, acc);
    __syncthreads();                      // reads done -> safe to overwrite tile
  }
}

// packed epilogue: lane writes 4 consecutive channels of one row as one 8B store
template<int NCT>
__device__ __forceinline__ void epi_swp(char* actc, int co0,
    const float* __restrict__ g, const float* __restrict__ bv, const float* __restrict__ bt,
    int lrow, int lkg, f32x4 (&acc)[4][NCT]){
  #pragma unroll
  for (int ct = 0; ct < NCT; ++ct){
    int co = co0 + ct*16 + lkg*4;
    float4 g4 = *(const float4*)(g + co);
    float4 b4 = *(const float4*)(bv + co);
    float4 t4 = *(const float4*)(bt + co);
    float sc0 = BN_RS*g4.x, sc1 = BN_RS*g4.y, sc2 = BN_RS*g4.z, sc3 = BN_RS*g4.w;
    float bb0 = b4.x*sc0 + t4.x, bb1 = b4.y*sc1 + t4.y;
    float bb2 = b4.z*sc2 + t4.z, bb3 = b4.w*sc3 + t4.w;
    #pragma unroll
    for (int mt = 0; mt < 4; ++mt){
      int r = mt*16 + lrow;
      h4v h;
      h[0] = (f16)silu_fast(acc[mt][ct][0]*sc0 + bb0);
      h[1] = (f16)silu_fast(acc[mt][ct][1]*sc1 + bb1);
      h[2] = (f16)silu_fast(acc[mt][ct][2]*sc2 + bb2);
      h[3] = (f16)silu_fast(acc[mt][ct][3]*sc3 + bb3);
      *(h4v*)(actc + swzb(r, co)) = h;
    }
  }
}

__global__ __launch_bounds__(1024) __attribute__((amdgpu_waves_per_eu(4, 4)))
void mlp_kernel(
    const f16* __restrict__ f9,
    const f16* __restrict__ c1t, const f16* __restrict__ resT,
    const f16* __restrict__ b0T, const f16* __restrict__ b1T, const f16* __restrict__ b2T,
    const float* __restrict__ c1_b, const float* __restrict__ c1_g, const float* __restrict__ c1_be,
    const float* __restrict__ res_b,
    const float* __restrict__ b0_b, const float* __restrict__ b0_g, const float* __restrict__ b0_be,
    const float* __restrict__ b1_b, const float* __restrict__ b1_g, const float* __restrict__ b1_be,
    const float* __restrict__ b2_b, const float* __restrict__ b2_g, const float* __restrict__ b2_be,
    unsigned* __restrict__ outmax){
  __shared__ __align__(16) f16 acts[2][64*512];   // 2 x 64 KiB act tiles (group 0 / group 1)
  __shared__ __align__(16) f16 wbuf[16384];       // 32 KiB shared weight tile
  const int tid  = threadIdx.x;
  const int wave = tid >> 6, lane = tid & 63;
  const int g = wave >> 3, w8 = wave & 7;         // group, col-group within group
  const int lrow = lane & 15, lkg = lane >> 4;
  const int bid = blockIdx.x;
  const int b = bid >> 9, k = (bid >> 4) & 31, n0 = (bid & 15) << 7;   // 128 rows/block
  char* actc = (char*)acts[g];

  // stage f9: 128 rows into the two act-tile front regions (cols 16..31 zero)
  if (tid < 512){
    int row = tid >> 2, part = tid & 3;
    h8v v;
    if (part < 2){
      const f16* src = f9 + (((size_t)(b*2048 + n0 + row) * 32 + k) << 4) + part*8;
      v = *(const h8v*)src;
    } else {
      #pragma unroll
      for (int t = 0; t < 8; ++t) v[t] = (f16)0.f;
    }
    *(h8v*)&acts[row >> 6][(row & 63)*32 + part*8] = v;
  }

  const f32x4 zf = {0.f, 0.f, 0.f, 0.f};
  f32x4 acc4[4][4];

  // ---- layer 1: Ci=32 (padded 9), Co=512 ----
  stage16<512, 32>(c1t, wbuf, 0, wave, lane);
  __syncthreads();                                 // f9 staged + weight tile ready
  #pragma unroll
  for (int mt = 0; mt < 4; ++mt)
    #pragma unroll
    for (int ct = 0; ct < 4; ++ct) acc4[mt][ct] = zf;
  {
    h8v a[4];
    #pragma unroll
    for (int mt = 0; mt < 4; ++mt)
      a[mt] = *(const h8v*)(actc + (mt*16 + lrow)*64 + lkg*16);
    #pragma unroll
    for (int ct = 0; ct < 4; ++ct){
      int ch = w8*64 + ct*16 + lrow;
      h8v w = *(const h8v*)((const char*)wbuf + woff(ch, lkg));
      #pragma unroll
      for (int mt = 0; mt < 4; ++mt)
        acc4[mt][ct] = __builtin_amdgcn_mfma_f32_16x16x32_f16(w, a[mt], acc4[mt][ct], 0, 0, 0);
    }
  }
  __syncthreads();                                 // reads of staged f9 + wbuf done
  epi_swp<4>(actc, w8*64, c1_g, c1_b, c1_be, lrow, lkg, acc4);
  __syncthreads();

  // ---- residual: f = h1 + (h1 @ res_w + res_b), in-place ----
  #pragma unroll
  for (int mt = 0; mt < 4; ++mt)
    #pragma unroll
    for (int ct = 0; ct < 4; ++ct) acc4[mt][ct] = zf;
  run_layer_sh<512, 512, 4>(resT, actc, wbuf, w8*64, wave, lane, lrow, lkg, acc4);
  #pragma unroll
  for (int ct = 0; ct < 4; ++ct){
    int co = w8*64 + ct*16 + lkg*4;
    float4 rb4 = *(const float4*)(res_b + co);
    #pragma unroll
    for (int mt = 0; mt < 4; ++mt){
      int r = mt*16 + lrow;
      h4v* p = (h4v*)(actc + swzb(r, co));        // lane-self-owned location
      h4v h = *p;
      h4v o;
      o[0] = (f16)((float)h[0] + acc4[mt][ct][0] + rb4.x);
      o[1] = (f16)((float)h[1] + acc4[mt][ct][1] + rb4.y);
      o[2] = (f16)((float)h[2] + acc4[mt][ct][2] + rb4.z);
      o[3] = (f16)((float)h[3] + acc4[mt][ct][3] + rb4.w);
      *p = o;
    }
  }
  __syncthreads();

  // ---- blk0: 512 -> 512, in-place ----
  #pragma unroll
  for (int mt = 0; mt < 4; ++mt)
    #pragma unroll
    for (int ct = 0; ct < 4; ++ct) acc4[mt][ct] = zf;
  run_layer_sh<512, 512, 4>(b0T, actc, wbuf, w8*64, wave, lane, lrow, lkg, acc4);
  epi_swp<4>(actc, w8*64, b0_g, b0_b, b0_be, lrow, lkg, acc4);
  __syncthreads();

  // ---- blk1: 512 -> 256, in-place (cols 0..255) ----
  f32x4 acc2[4][2];
  #pragma unroll
  for (int mt = 0; mt < 4; ++mt){ acc2[mt][0] = zf; acc2[mt][1] = zf; }
  run_layer_sh<256, 512, 2>(b1T, actc, wbuf, w8*32, wave, lane, lrow, lkg, acc2);
  epi_swp<2>(actc, w8*32, b1_g, b1_b, b1_be, lrow, lkg, acc2);
  __syncthreads();

  // ---- blk2: 256 -> 170 (pad 176), acts as A-operand, + row-max + atomic ----
  f32x4 acc3[4][2];
  #pragma unroll
  for (int mt = 0; mt < 4; ++mt){ acc3[mt][0] = zf; acc3[mt][1] = zf; }
  {
    const int xr = (lrow & 7) << 4;
    const bool has2 = (w8 + 8) < 11;
    #pragma unroll
    for (int t = 0; t < 8; ++t){
      stage16<176, 256>(b2T, wbuf, t, wave, lane);
      __syncthreads();
      h8v a[4];
      int koff = ((t*4 + lkg) << 4) ^ xr;
      #pragma unroll
      for (int mt = 0; mt < 4; ++mt)
        a[mt] = *(const h8v*)(actc + (mt*16 + lrow)*1024 + koff);
      {
        int ch = w8*16 + lrow;
        h8v w = *(const h8v*)((const char*)wbuf + woff(ch, lkg));
        #pragma unroll
        for (int mt = 0; mt < 4; ++mt)
          acc3[mt][0] = __builtin_amdgcn_mfma_f32_16x16x32_f16(a[mt], w, acc3[mt][0], 0, 0, 0);
      }
      if (has2){
        int ch = (w8 + 8)*16 + lrow;
        h8v w = *(const h8v*)((const char*)wbuf + woff(ch, lkg));
        #pragma unroll
        for (int mt = 0; mt < 4; ++mt)
          acc3[mt][1] = __builtin_amdgcn_mfma_f32_16x16x32_f16(a[mt], w, acc3[mt][1], 0, 0, 0);
      }
      __syncthreads();
    }
    #pragma unroll
    for (int t = 0; t < 2; ++t){
      if (t == 1 && !has2) break;
      int c = ((t == 0) ? w8 : w8 + 8)*16 + lrow;
      if (c < 170){
        float sc = BN_RS * b2_g[c];
        float bb = b2_b[c]*sc + b2_be[c];
        float mx = -INFINITY;
        #pragma unroll
        for (int mt = 0; mt < 4; ++mt)
          #pragma unroll
          for (int rg = 0; rg < 4; ++rg)
            mx = fmaxf(mx, silu_fast(acc3[mt][t][rg]*sc + bb));
        mx = fmaxf(mx, __shfl_xor(mx, 16));
        mx = fmaxf(mx, __shfl_xor(mx, 32));
        if (lkg == 0)
          atomicMax(&outmax[b*5440 + k*170 + c], f2mono(mx));
      }
    }
  }
}

__global__ void finalize_kernel(const unsigned* __restrict__ m, float* __restrict__ out, int n){
  int i = blockIdx.x*blockDim.x + threadIdx.x;
  if (i < n) out[i] = mono2f(m[i]);
}

// ---------------- launch ----------------
extern "C" void kernel_launch(void* const* d_in, const int* in_sizes, int n_in,
                              void* d_out, int out_size, void* d_ws, size_t ws_size,
                              hipStream_t stream){
  const float* pts    = (const float*)d_in[0];
  const float* t_cw   = (const float*)d_in[1];
  const float* t_cb   = (const float*)d_in[2];
  const float* t_g1   = (const float*)d_in[3];
  const float* t_b1   = (const float*)d_in[4];
  const float* t_d1w  = (const float*)d_in[5];
  const float* t_d1b  = (const float*)d_in[6];
  const float* t_g2   = (const float*)d_in[7];
  const float* t_b2   = (const float*)d_in[8];
  const float* t_d2w  = (const float*)d_in[9];
  const float* t_d2b  = (const float*)d_in[10];
  const float* c1_w   = (const float*)d_in[11];
  const float* c1_b   = (const float*)d_in[12];
  const float* c1_g   = (const float*)d_in[13];
  const float* c1_be  = (const float*)d_in[14];
  const float* res_w  = (const float*)d_in[15];
  const float* res_b  = (const float*)d_in[16];
  const float* b0_w   = (const float*)d_in[17];
  const float* b0_b   = (const float*)d_in[18];
  const float* b0_g   = (const float*)d_in[19];
  const float* b0_be  = (const float*)d_in[20];
  const float* b1_w   = (const float*)d_in[21];
  const float* b1_b   = (const float*)d_in[22];
  const float* b1_g   = (const float*)d_in[23];
  const float* b1_be  = (const float*)d_in[24];
  const float* b2_w   = (const float*)d_in[25];
  const float* b2_b   = (const float*)d_in[26];
  const float* b2_g   = (const float*)d_in[27];
  const float* b2_be  = (const float*)d_in[28];

  char* ws = (char*)d_ws;
  float*    T9   = (float*)(ws + OFF_T9);
  unsigned* XM   = (unsigned*)(ws + OFF_XM);
  float4*   PC4  = (float4*)(ws + OFF_PC4);
  unsigned* OUTM = (unsigned*)(ws + OFF_OUT);
  f16* C1T  = (f16*)(ws + OFF_C1T);
  f16* REST = (f16*)(ws + OFF_REST);
  f16* B0T  = (f16*)(ws + OFF_B0T);
  f16* B1T  = (f16*)(ws + OFF_B1T);
  f16* B2T  = (f16*)(ws + OFF_B2T);
  f16* F9   = (f16*)(ws + OFF_F9);

  hipMemsetAsync(ws + OFF_XM, 0, 4*128*4, stream);
  hipMemsetAsync(ws + OFF_OUT, 0, 21760*4, stream);

  prep_kernel<<<512, 256, 0, stream>>>(c1_w, res_w, b0_w, b1_w, b2_w, C1T, REST, B0T, B1T, B2T);
  tnet1_kernel<<<dim3(4,4), dim3(128,4), 0, stream>>>(pts, t_cw, t_cb, t_g1, t_b1, XM);
  tnet2_kernel<<<4, 128, 0, stream>>>(XM, t_d1w, t_d1b, t_g2, t_b2, t_d2w, t_d2b, T9);
  pc_kernel<<<32, 256, 0, stream>>>(pts, T9, PC4);
  group_kernel<<<2048, 256, 0, stream>>>(PC4, F9);
  mlp_kernel<<<2048, 1024, 0, stream>>>(F9, C1T, REST, B0T, B1T, B2T,
                                        c1_b, c1_g, c1_be, res_b,
                                        b0_b, b0_g, b0_be,
                                        b1_b, b1_g, b1_be,
                                        b2_b, b2_g, b2_be, OUTM);
  finalize_kernel<<<(out_size + 255)/256, 256, 0, stream>>>(OUTM, (float*)d_out, out_size);
}

// Round 8
// 601.932 us; speedup vs baseline: 1.9104x; 1.7524x over previous
//
#include <hip/hip_runtime.h>
#include <math.h>

#define BN_RS 0.9995003746877732f

typedef unsigned short u16;
typedef _Float16 f16;
typedef __attribute__((ext_vector_type(8))) _Float16 h8v;     // 8 f16 (A/B frag)
typedef __attribute__((ext_vector_type(4))) _Float16 h4v;     // packed 4 f16 (8B)
typedef __attribute__((ext_vector_type(4))) float f32x4;      // C/D frag

// ---------------- helpers ----------------
__device__ __forceinline__ unsigned f2mono(float f){
  unsigned u = __float_as_uint(f);
  return (u & 0x80000000u) ? ~u : (u | 0x80000000u);
}
__device__ __forceinline__ float mono2f(unsigned m){
  unsigned u = (m & 0x80000000u) ? (m & 0x7FFFFFFFu) : ~m;
  return __uint_as_float(u);
}
__device__ __forceinline__ float silu_fast(float x){ return x / (1.f + __expf(-x)); }
__device__ __forceinline__ float silu_f64(float x){
  double e = exp(-(double)x);
  return (float)((double)x / (1.0 + e));
}

// ---------------- ws layout (bytes) ----------------
constexpr size_t OFF_T9   = 0;         //  4*9*4
constexpr size_t OFF_XM   = 1024;      //  4*128*4 (mono uints)
constexpr size_t OFF_PC4  = 4096;      //  8192*16
constexpr size_t OFF_OUT  = 139264;    //  21760*4
constexpr size_t OFF_C1T  = 227328;    //  512*32*2   (frag-packed)
constexpr size_t OFF_REST = 262144;    //  512*512*2  (frag-packed)
constexpr size_t OFF_B0T  = 786432;    //  512*512*2  (frag-packed)
constexpr size_t OFF_B1T  = 1310720;   //  256*512*2  (frag-packed)
constexpr size_t OFF_B2T  = 1572864;   //  176*256*2  (frag-packed)
constexpr size_t OFF_F9   = 1703936;   //  8192*32*16*2

// ---------------- T-Net stage 1 ----------------
__global__ void tnet1_kernel(const float* __restrict__ pts, const float* __restrict__ t_cw,
                             const float* __restrict__ t_cb, const float* __restrict__ t_g1,
                             const float* __restrict__ t_b1, unsigned* __restrict__ xm_mono){
  int u = threadIdx.x;                 // 0..127
  int b = blockIdx.x;                  // 0..3
  int slice = blockIdx.y * blockDim.y + threadIdx.y;   // 0..15
  float w0 = t_cw[u], w1 = t_cw[128+u], w2 = t_cw[256+u];
  float cb = t_cb[u];
  float sc = __fmul_rn(BN_RS, t_g1[u]);
  float b1 = t_b1[u];
  float mx = -INFINITY;
  const float* P = pts + ((size_t)b*2048 + (size_t)slice*128)*3;
  for (int n = 0; n < 128; ++n){
    float y = __fadd_rn(__fadd_rn(__fmul_rn(P[n*3+0], w0), __fmul_rn(P[n*3+1], w1)),
                        __fmul_rn(P[n*3+2], w2));
    y = __fadd_rn(y, cb);
    y = __fadd_rn(__fmul_rn(y, sc), b1);
    mx = fmaxf(mx, silu_f64(y));
  }
  atomicMax(&xm_mono[b*128+u], f2mono(mx));
}

// ---------------- T-Net stage 2 (f64 accum) ----------------
__global__ void tnet2_kernel(const unsigned* __restrict__ xm_mono,
                             const float* __restrict__ d1w, const float* __restrict__ d1b,
                             const float* __restrict__ g2, const float* __restrict__ b2,
                             const float* __restrict__ d2w, const float* __restrict__ d2b,
                             float* __restrict__ T9){
  __shared__ float xs[128], x2s[128];
  int u = threadIdx.x, b = blockIdx.x;
  xs[u] = mono2f(xm_mono[b*128+u]);
  __syncthreads();
  double acc = (double)d1b[u];
  for (int v = 0; v < 128; ++v) acc += (double)xs[v] * (double)d1w[v*128+u];
  double sc = (double)__fmul_rn(BN_RS, g2[u]);
  acc = acc*sc + (double)b2[u];
  double e = exp(-acc);
  x2s[u] = (float)(acc / (1.0 + e));
  __syncthreads();
  if (u < 9){
    double t = (double)d2b[u];
    for (int v = 0; v < 128; ++v) t += (double)x2s[v] * (double)d2w[v*9+u];
    T9[b*9+u] = (float)t;
  }
}

// ---------------- pc = pts @ T (np order, no fma) + sq ----------------
__global__ void pc_kernel(const float* __restrict__ pts, const float* __restrict__ T9,
                          float4* __restrict__ pc4){
  int i = blockIdx.x*blockDim.x + threadIdx.x;   // 0..8191
  int b = i >> 11;
  const float* p = pts + (size_t)i*3;
  float x = p[0], y = p[1], z = p[2];
  const float* T = T9 + b*9;
  float px = __fadd_rn(__fadd_rn(__fmul_rn(x, T[0]), __fmul_rn(y, T[3])), __fmul_rn(z, T[6]));
  float py = __fadd_rn(__fadd_rn(__fmul_rn(x, T[1]), __fmul_rn(y, T[4])), __fmul_rn(z, T[7]));
  float pz = __fadd_rn(__fadd_rn(__fmul_rn(x, T[2]), __fmul_rn(y, T[5])), __fmul_rn(z, T[8]));
  float sq = __fadd_rn(__fadd_rn(__fmul_rn(px, px), __fmul_rn(py, py)), __fmul_rn(pz, pz));
  pc4[i] = make_float4(px, py, pz, sq);
}

// ---------------- grouping ----------------
__global__ __launch_bounds__(256) void group_kernel(const float4* __restrict__ pc4,
                                                    f16* __restrict__ f9){
  __shared__ float4 pcl[2048];
  __shared__ int ones[4][3][32];
  __shared__ int zer [4][3][32];
  const float RAD[3] = {0.1f, 0.3f, 0.5f};
  int tid = threadIdx.x, wave = tid >> 6, lane = tid & 63;
  int bid = blockIdx.x;
  int b = bid >> 9, n0 = (bid & 511) * 4;
  const float4* src = pc4 + (size_t)b*2048;
  for (int x = tid; x < 2048; x += 256) pcl[x] = src[x];
  __syncthreads();

  int n = n0 + wave;
  float4 pi = pcl[n];
  float xi = pi.x, yi = pi.y, zi = pi.z, sqi = pi.w;
  int c1[3] = {0,0,0}, c0[3] = {0,0,0};
  unsigned long long lt = (1ULL << lane) - 1ULL;

  for (int ch = 0; ch < 32; ++ch){
    int j = ch*64 + lane;
    float4 pj = pcl[j];
    float dot = __fadd_rn(__fadd_rn(__fmul_rn(xi, pj.x), __fmul_rn(yi, pj.y)),
                          __fmul_rn(zi, pj.z));
    float d2 = __fsub_rn(__fadd_rn(sqi, pj.w), __fmul_rn(2.f, dot));
    float dist = sqrtf(fmaxf(d2, 0.f));
    #pragma unroll
    for (int ri = 0; ri < 3; ++ri){
      bool in = (dist <= RAD[ri]);
      unsigned long long m = __ballot(in);
      int pc_lt = (int)__popcll(m & lt);
      if (c1[ri] < 32){
        int pos = c1[ri] + pc_lt;
        if (in && pos < 32) ones[wave][ri][pos] = j;
      }
      if (c0[ri] < 32){
        int pos = c0[ri] + (int)(lane - pc_lt);
        if (!in && pos < 32) zer[wave][ri][pos] = j;
      }
      int t1 = (int)__popcll(m);
      c1[ri] += t1;
      c0[ri] += 64 - t1;
    }
    if (c1[0] >= 32 && c1[1] >= 32 && c1[2] >= 32 &&
        c0[0] >= 32 && c0[1] >= 32 && c0[2] >= 32) break;
  }
  __syncthreads();

  if (lane < 32){
    h8v va, vb;
    #pragma unroll
    for (int t = 0; t < 8; ++t){ va[t] = (f16)0.f; vb[t] = (f16)0.f; }
    #pragma unroll
    for (int ri = 0; ri < 3; ++ri){
      int cc = c1[ri] < 32 ? c1[ri] : 32;
      int sel = (lane < cc) ? ones[wave][ri][lane] : zer[wave][ri][lane - cc];
      float4 p = pcl[sel];
      if (ri == 0){ va[0]=(f16)p.x; va[1]=(f16)p.y; va[2]=(f16)p.z; }
      if (ri == 1){ va[3]=(f16)p.x; va[4]=(f16)p.y; va[5]=(f16)p.z; }
      if (ri == 2){ va[6]=(f16)p.x; va[7]=(f16)p.y; vb[0]=(f16)p.z; }
    }
    f16* dst = f9 + (((size_t)(b*2048 + n) * 32 + lane) << 4);
    *(h8v*)dst = va;
    *(h8v*)(dst + 8) = vb;
  }
}

// ---------------- weight prep: fragment-order pack ----------------
// dst[((sct*NT + t)*64 + lane)*8 + j] = W[ci][co], co = sct*16 + (lane&15),
// ci = t*32 + (lane>>4)*8 + j  (0 beyond real dims). One lane-load = one MFMA frag.
__device__ __forceinline__ void pack_frag(const float* __restrict__ src, f16* __restrict__ dst,
                                          int CO, int CI, int COr, int CIr,
                                          int i0, int stride){
  int NT = CI >> 5;
  int total = (CO >> 4) * NT * 512;
  for (int x = i0; x < total; x += stride){
    int j = x & 7, lane = (x >> 3) & 63;
    int t = (x >> 9) % NT, sct = x / (NT << 9);
    int co = sct*16 + (lane & 15);
    int ci = t*32 + (lane >> 4)*8 + j;
    float v = (co < COr && ci < CIr) ? src[ci*COr + co] : 0.f;
    dst[x] = (f16)v;
  }
}

__global__ void prep_kernel(const float* __restrict__ c1w, const float* __restrict__ resw,
                            const float* __restrict__ b0w, const float* __restrict__ b1w,
                            const float* __restrict__ b2w,
                            f16* __restrict__ c1F, f16* __restrict__ resF, f16* __restrict__ b0F,
                            f16* __restrict__ b1F, f16* __restrict__ b2F){
  int i0 = blockIdx.x*blockDim.x + threadIdx.x;
  int stride = gridDim.x*blockDim.x;
  pack_frag(c1w,  c1F,  512,  32, 512,   9, i0, stride);
  pack_frag(resw, resF, 512, 512, 512, 512, i0, stride);
  pack_frag(b0w,  b0F,  512, 512, 512, 512, i0, stride);
  pack_frag(b1w,  b1F,  256, 512, 256, 512, i0, stride);
  pack_frag(b2w,  b2F,  176, 256, 170, 256, i0, stride);
}

// ---------------- MLP ----------------
// act tile: 64 rows x 512 f16, stride 1024 B, XOR-swizzled by ((row&7)<<4)
__device__ __forceinline__ int swzb(int row, int c){
  return (row*1024 + c*2) ^ ((row & 7) << 4);
}

// register-streamed layer: acts from LDS, weights straight from global (frag-packed,
// coalesced lane*16), MFMAs; NO barriers inside — compiler pipelines freely.
template<int NT, int NCT>
__device__ __forceinline__ void mm_stream(const char* actc, const f16* __restrict__ WF,
                                          int sct0, int lane, int lrow, int lkg,
                                          f32x4 (&acc)[4][NCT]){
  const int xr = (lrow & 7) << 4;
  #pragma unroll
  for (int t = 0; t < NT; ++t){
    h8v a[4];
    int koff = ((t*4 + lkg) << 4) ^ xr;
    #pragma unroll
    for (int mt = 0; mt < 4; ++mt)
      a[mt] = *(const h8v*)(actc + (mt*16 + lrow)*1024 + koff);
    #pragma unroll
    for (int ct = 0; ct < NCT; ++ct){
      h8v w = *(const h8v*)&WF[((size_t)((sct0 + ct)*NT + t)*64 + lane)*8];
      #pragma unroll
      for (int mt = 0; mt < 4; ++mt)
        acc[mt][ct] = __builtin_amdgcn_mfma_f32_16x16x32_f16(w, a[mt], acc[mt][ct], 0, 0, 0);
    }
  }
}

// packed epilogue: lane writes 4 consecutive channels of one row as one 8B store
template<int NCT>
__device__ __forceinline__ void epi_swp(char* actc, int co0,
    const float* __restrict__ g, const float* __restrict__ bv, const float* __restrict__ bt,
    int lrow, int lkg, f32x4 (&acc)[4][NCT]){
  #pragma unroll
  for (int ct = 0; ct < NCT; ++ct){
    int co = co0 + ct*16 + lkg*4;
    float4 g4 = *(const float4*)(g + co);
    float4 b4 = *(const float4*)(bv + co);
    float4 t4 = *(const float4*)(bt + co);
    float sc0 = BN_RS*g4.x, sc1 = BN_RS*g4.y, sc2 = BN_RS*g4.z, sc3 = BN_RS*g4.w;
    float bb0 = b4.x*sc0 + t4.x, bb1 = b4.y*sc1 + t4.y;
    float bb2 = b4.z*sc2 + t4.z, bb3 = b4.w*sc3 + t4.w;
    #pragma unroll
    for (int mt = 0; mt < 4; ++mt){
      int r = mt*16 + lrow;
      h4v h;
      h[0] = (f16)silu_fast(acc[mt][ct][0]*sc0 + bb0);
      h[1] = (f16)silu_fast(acc[mt][ct][1]*sc1 + bb1);
      h[2] = (f16)silu_fast(acc[mt][ct][2]*sc2 + bb2);
      h[3] = (f16)silu_fast(acc[mt][ct][3]*sc3 + bb3);
      *(h4v*)(actc + swzb(r, co)) = h;
    }
  }
}

__global__ __launch_bounds__(512, 2) void mlp_kernel(
    const f16* __restrict__ f9,
    const f16* __restrict__ c1F, const f16* __restrict__ resF,
    const f16* __restrict__ b0F, const f16* __restrict__ b1F, const f16* __restrict__ b2F,
    const float* __restrict__ c1_b, const float* __restrict__ c1_g, const float* __restrict__ c1_be,
    const float* __restrict__ res_b,
    const float* __restrict__ b0_b, const float* __restrict__ b0_g, const float* __restrict__ b0_be,
    const float* __restrict__ b1_b, const float* __restrict__ b1_g, const float* __restrict__ b1_be,
    const float* __restrict__ b2_b, const float* __restrict__ b2_g, const float* __restrict__ b2_be,
    unsigned* __restrict__ outmax){
  __shared__ __align__(16) f16 buf[64*512];       // 64 KiB acts, in-place across layers
  char* actc = (char*)buf;
  const int tid  = threadIdx.x;
  const int wave = tid >> 6, lane = tid & 63;
  const int lrow = lane & 15, lkg = lane >> 4;
  const int bid = blockIdx.x;
  const int b = bid >> 10, k = (bid >> 5) & 31, n0 = (bid & 31) << 6;

  // stage f9 rows [64][32] into buf front region (cols 16..31 zero)
  if (tid < 256){
    int row = tid >> 2, part = tid & 3;
    h8v v;
    if (part < 2){
      const f16* src = f9 + (((size_t)(b*2048 + n0 + row) * 32 + k) << 4) + part*8;
      v = *(const h8v*)src;
    } else {
      #pragma unroll
      for (int t = 0; t < 8; ++t) v[t] = (f16)0.f;
    }
    *(h8v*)&buf[row*32 + part*8] = v;
  }
  __syncthreads();

  const f32x4 zf = {0.f, 0.f, 0.f, 0.f};
  f32x4 acc4[4][4];

  // ---- layer 1: Ci=32 (padded 9), Co=512, acts from packed [64][32] region ----
  #pragma unroll
  for (int mt = 0; mt < 4; ++mt)
    #pragma unroll
    for (int ct = 0; ct < 4; ++ct) acc4[mt][ct] = zf;
  {
    h8v a[4];
    #pragma unroll
    for (int mt = 0; mt < 4; ++mt)
      a[mt] = *(const h8v*)(actc + (mt*16 + lrow)*64 + lkg*16);
    #pragma unroll
    for (int ct = 0; ct < 4; ++ct){
      h8v w = *(const h8v*)&c1F[((size_t)(wave*4 + ct)*64 + lane)*8];
      #pragma unroll
      for (int mt = 0; mt < 4; ++mt)
        acc4[mt][ct] = __builtin_amdgcn_mfma_f32_16x16x32_f16(w, a[mt], acc4[mt][ct], 0, 0, 0);
    }
  }
  __syncthreads();                                 // reads of staged f9 done
  epi_swp<4>(actc, wave*64, c1_g, c1_b, c1_be, lrow, lkg, acc4);
  __syncthreads();

  // ---- residual: f = h1 + (h1 @ res_w + res_b), in-place ----
  #pragma unroll
  for (int mt = 0; mt < 4; ++mt)
    #pragma unroll
    for (int ct = 0; ct < 4; ++ct) acc4[mt][ct] = zf;
  mm_stream<16, 4>(actc, resF, wave*4, lane, lrow, lkg, acc4);
  __syncthreads();                                 // all reads of h1 done
  #pragma unroll
  for (int ct = 0; ct < 4; ++ct){
    int co = wave*64 + ct*16 + lkg*4;
    float4 rb4 = *(const float4*)(res_b + co);
    #pragma unroll
    for (int mt = 0; mt < 4; ++mt){
      int r = mt*16 + lrow;
      h4v* p = (h4v*)(actc + swzb(r, co));        // lane-self-owned location
      h4v h = *p;
      h4v o;
      o[0] = (f16)((float)h[0] + acc4[mt][ct][0] + rb4.x);
      o[1] = (f16)((float)h[1] + acc4[mt][ct][1] + rb4.y);
      o[2] = (f16)((float)h[2] + acc4[mt][ct][2] + rb4.z);
      o[3] = (f16)((float)h[3] + acc4[mt][ct][3] + rb4.w);
      *p = o;
    }
  }
  __syncthreads();

  // ---- blk0: 512 -> 512, in-place ----
  #pragma unroll
  for (int mt = 0; mt < 4; ++mt)
    #pragma unroll
    for (int ct = 0; ct < 4; ++ct) acc4[mt][ct] = zf;
  mm_stream<16, 4>(actc, b0F, wave*4, lane, lrow, lkg, acc4);
  __syncthreads();
  epi_swp<4>(actc, wave*64, b0_g, b0_b, b0_be, lrow, lkg, acc4);
  __syncthreads();

  // ---- blk1: 512 -> 256, in-place (cols 0..255) ----
  f32x4 acc2[4][2];
  #pragma unroll
  for (int mt = 0; mt < 4; ++mt){ acc2[mt][0] = zf; acc2[mt][1] = zf; }
  mm_stream<16, 2>(actc, b1F, wave*2, lane, lrow, lkg, acc2);
  __syncthreads();
  epi_swp<2>(actc, wave*32, b1_g, b1_b, b1_be, lrow, lkg, acc2);
  __syncthreads();

  // ---- blk2: 256 -> 170 (pad 176), acts as A-operand, + row-max + atomic ----
  f32x4 acc3[4][2];
  #pragma unroll
  for (int mt = 0; mt < 4; ++mt){ acc3[mt][0] = zf; acc3[mt][1] = zf; }
  {
    const int xr = (lrow & 7) << 4;
    const bool has2 = wave < 3;                    // wave+8 < 11
    #pragma unroll
    for (int t = 0; t < 8; ++t){
      h8v a[4];
      int koff = ((t*4 + lkg) << 4) ^ xr;
      #pragma unroll
      for (int mt = 0; mt < 4; ++mt)
        a[mt] = *(const h8v*)(actc + (mt*16 + lrow)*1024 + koff);
      {
        h8v w = *(const h8v*)&b2F[((size_t)(wave*8 + t)*64 + lane)*8];
        #pragma unroll
        for (int mt = 0; mt < 4; ++mt)
          acc3[mt][0] = __builtin_amdgcn_mfma_f32_16x16x32_f16(a[mt], w, acc3[mt][0], 0, 0, 0);
      }
      if (has2){
        h8v w = *(const h8v*)&b2F[((size_t)((wave + 8)*8 + t)*64 + lane)*8];
        #pragma unroll
        for (int mt = 0; mt < 4; ++mt)
          acc3[mt][1] = __builtin_amdgcn_mfma_f32_16x16x32_f16(a[mt], w, acc3[mt][1], 0, 0, 0);
      }
    }
    #pragma unroll
    for (int t = 0; t < 2; ++t){
      if (t == 1 && !has2) break;
      int c = ((t == 0) ? wave : wave + 8)*16 + lrow;
      if (c < 170){
        float sc = BN_RS * b2_g[c];
        float bb = b2_b[c]*sc + b2_be[c];
        float mx = -INFINITY;
        #pragma unroll
        for (int mt = 0; mt < 4; ++mt)
          #pragma unroll
          for (int rg = 0; rg < 4; ++rg)
            mx = fmaxf(mx, silu_fast(acc3[mt][t][rg]*sc + bb));
        mx = fmaxf(mx, __shfl_xor(mx, 16));
        mx = fmaxf(mx, __shfl_xor(mx, 32));
        if (lkg == 0)
          atomicMax(&outmax[b*5440 + k*170 + c], f2mono(mx));
      }
    }
  }
}

__global__ void finalize_kernel(const unsigned* __restrict__ m, float* __restrict__ out, int n){
  int i = blockIdx.x*blockDim.x + threadIdx.x;
  if (i < n) out[i] = mono2f(m[i]);
}

// ---------------- launch ----------------
extern "C" void kernel_launch(void* const* d_in, const int* in_sizes, int n_in,
                              void* d_out, int out_size, void* d_ws, size_t ws_size,
                              hipStream_t stream){
  const float* pts    = (const float*)d_in[0];
  const float* t_cw   = (const float*)d_in[1];
  const float* t_cb   = (const float*)d_in[2];
  const float* t_g1   = (const float*)d_in[3];
  const float* t_b1   = (const float*)d_in[4];
  const float* t_d1w  = (const float*)d_in[5];
  const float* t_d1b  = (const float*)d_in[6];
  const float* t_g2   = (const float*)d_in[7];
  const float* t_b2   = (const float*)d_in[8];
  const float* t_d2w  = (const float*)d_in[9];
  const float* t_d2b  = (const float*)d_in[10];
  const float* c1_w   = (const float*)d_in[11];
  const float* c1_b   = (const float*)d_in[12];
  const float* c1_g   = (const float*)d_in[13];
  const float* c1_be  = (const float*)d_in[14];
  const float* res_w  = (const float*)d_in[15];
  const float* res_b  = (const float*)d_in[16];
  const float* b0_w   = (const float*)d_in[17];
  const float* b0_b   = (const float*)d_in[18];
  const float* b0_g   = (const float*)d_in[19];
  const float* b0_be  = (const float*)d_in[20];
  const float* b1_w   = (const float*)d_in[21];
  const float* b1_b   = (const float*)d_in[22];
  const float* b1_g   = (const float*)d_in[23];
  const float* b1_be  = (const float*)d_in[24];
  const float* b2_w   = (const float*)d_in[25];
  const float* b2_b   = (const float*)d_in[26];
  const float* b2_g   = (const float*)d_in[27];
  const float* b2_be  = (const float*)d_in[28];

  char* ws = (char*)d_ws;
  float*    T9   = (float*)(ws + OFF_T9);
  unsigned* XM   = (unsigned*)(ws + OFF_XM);
  float4*   PC4  = (float4*)(ws + OFF_PC4);
  unsigned* OUTM = (unsigned*)(ws + OFF_OUT);
  f16* C1F  = (f16*)(ws + OFF_C1T);
  f16* RESF = (f16*)(ws + OFF_REST);
  f16* B0F  = (f16*)(ws + OFF_B0T);
  f16* B1F  = (f16*)(ws + OFF_B1T);
  f16* B2F  = (f16*)(ws + OFF_B2T);
  f16* F9   = (f16*)(ws + OFF_F9);

  hipMemsetAsync(ws + OFF_XM, 0, 4*128*4, stream);
  hipMemsetAsync(ws + OFF_OUT, 0, 21760*4, stream);

  prep_kernel<<<512, 256, 0, stream>>>(c1_w, res_w, b0_w, b1_w, b2_w, C1F, RESF, B0F, B1F, B2F);
  tnet1_kernel<<<dim3(4,4), dim3(128,4), 0, stream>>>(pts, t_cw, t_cb, t_g1, t_b1, XM);
  tnet2_kernel<<<4, 128, 0, stream>>>(XM, t_d1w, t_d1b, t_g2, t_b2, t_d2w, t_d2b, T9);
  pc_kernel<<<32, 256, 0, stream>>>(pts, T9, PC4);
  group_kernel<<<2048, 256, 0, stream>>>(PC4, F9);
  mlp_kernel<<<4096, 512, 0, stream>>>(F9, C1F, RESF, B0F, B1F, B2F,
                                       c1_b, c1_g, c1_be, res_b,
                                       b0_b, b0_g, b0_be,
                                       b1_b, b1_g, b1_be,
                                       b2_b, b2_g, b2_be, OUTM);
  finalize_kernel<<<(out_size + 255)/256, 256, 0, stream>>>(OUTM, (float*)d_out, out_size);
}